// Round 2
// baseline (144.948 us; speedup 1.0000x reference)
//
#include <hip/hip_runtime.h>

// Helmholtz: out = laplacian(x)/h^2 - kappa^2*OMEGA*(OMEGA - i*gamma)*x
// Logical shape: B=8, images 1024x1024, h=1/1024 -> 1/h^2 = 1048576.
//
// Layout-adaptive + fully bounds-guarded version: round 1 core-dumped (likely
// GPU memory fault), so this round derives every extent from runtime sizes and
// never touches a byte beyond min(assumed, reported) — while handling the three
// plausible complex64 representations.

#define NCOL 1024
#define NROWIMG 1024
#define H2 1048576.0f
#define OMG 80.0f

// world: 0 = x interleaved float pairs (complex64 viewed as float32)
//        1 = x planar: xa=real plane, xb=imag plane
//        2 = x real-only floats (only nk floats guaranteed readable)
// omode: 0 = out interleaved float pairs, 1 = out planar (re plane then im),
//        2 = out real plane only (only nk floats guaranteed writable)
__global__ __launch_bounds__(256) void helm_adapt(
    const float* __restrict__ xa,
    const float* __restrict__ xb,
    const float* __restrict__ kap,
    const float* __restrict__ gma,
    float* __restrict__ out,
    int nk, int world, int omode)
{
    const int e = blockIdx.x * blockDim.x + threadIdx.x;   // complex-element idx
    if (e >= nk) return;
    const int col = e & (NCOL - 1);
    const int row = e >> 10;               // global row (b*1024 + i)
    const int i   = row & (NROWIMG - 1);   // row within image

    float cr, ci;
    float ur = 0.f, ui = 0.f, dr = 0.f, di = 0.f;
    float lr = 0.f, li = 0.f, rr = 0.f, ri = 0.f;

    if (world == 0) {
        const float2* x2 = (const float2*)xa;          // nk complex = 2*nk floats
        float2 c = x2[e]; cr = c.x; ci = c.y;
        if (i > 0)          { float2 t = x2[e - NCOL]; ur = t.x; ui = t.y; }
        if (i < NROWIMG - 1){ float2 t = x2[e + NCOL]; dr = t.x; di = t.y; }
        if (col > 0)        { float2 t = x2[e - 1];    lr = t.x; li = t.y; }
        if (col < NCOL - 1) { float2 t = x2[e + 1];    rr = t.x; ri = t.y; }
    } else if (world == 1) {
        cr = xa[e]; ci = xb[e];
        if (i > 0)          { ur = xa[e - NCOL]; ui = xb[e - NCOL]; }
        if (i < NROWIMG - 1){ dr = xa[e + NCOL]; di = xb[e + NCOL]; }
        if (col > 0)        { lr = xa[e - 1];    li = xb[e - 1]; }
        if (col < NCOL - 1) { rr = xa[e + 1];    ri = xb[e + 1]; }
    } else {
        cr = xa[e]; ci = 0.f;
        if (i > 0)          ur = xa[e - NCOL];
        if (i < NROWIMG - 1) dr = xa[e + NCOL];
        if (col > 0)        lr = xa[e - 1];
        if (col < NCOL - 1) rr = xa[e + 1];
    }

    const float kk = kap[e];
    const float gg = gma[e];

    const float lapr = (4.f * cr - ur - dr - lr - rr) * H2;
    const float lapi = (4.f * ci - ui - di - li - ri) * H2;
    const float ks = kk * kk;
    const float hr = OMG * OMG * ks;     // Re(helm)
    const float hi = -OMG * ks * gg;     // Im(helm)
    const float or_ = lapr - (hr * cr - hi * ci);
    const float oi_ = lapi - (hr * ci + hi * cr);

    if (omode == 0) {
        ((float2*)out)[e] = make_float2(or_, oi_);     // floats [0, 2*nk)
    } else if (omode == 1) {
        out[e] = or_;                                  // re plane
        out[nk + e] = oi_;                             // im plane
    } else {
        out[e] = or_;                                  // only nk floats writable
    }
}

extern "C" void kernel_launch(void* const* d_in, const int* in_sizes, int n_in,
                              void* d_out, int out_size, void* d_ws, size_t ws_size,
                              hipStream_t stream) {
    // kappa is always the second-to-last input and is plain float32: its size
    // is the unambiguous complex-element count (B*M*N = 8,388,608).
    const int nk = in_sizes[n_in - 2];
    const float* kap = (const float*)d_in[n_in - 2];
    const float* gma = (const float*)d_in[n_in - 1];
    const float* xa  = (const float*)d_in[0];
    const float* xb  = nullptr;

    int world;
    if (n_in >= 4) {                 // complex split into planar re/im inputs
        world = 1;
        xb = (const float*)d_in[1];
    } else if (in_sizes[0] >= 2 * nk) {
        world = 0;                   // interleaved float32 view of complex64
    } else {
        world = 2;                   // only nk floats guaranteed readable
    }

    int omode;
    if (out_size >= 2 * nk) {
        omode = (world == 1) ? 1 : 0;   // mirror input representation
    } else {
        omode = 2;                      // only nk floats guaranteed writable
    }

    const int block = 256;
    const int grid = (nk + block - 1) / block;
    helm_adapt<<<grid, block, 0, stream>>>(xa, xb, kap, gma, (float*)d_out,
                                           nk, world, omode);
}

// Round 3
// 143.927 us; speedup vs baseline: 1.0071x; 1.0071x over previous
//
#include <hip/hip_runtime.h>

// Helmholtz: out = laplacian(x)/h^2 - kappa^2*OMEGA*(OMEGA - i*gamma)*x
// B=8, 1024x1024 images, h=1/1024 -> 1/h^2 = 1048576.
// Confirmed layout (round 2): x is interleaved complex64 (in_sizes[0]==2*nk
// floats), out is interleaved complex64 (out_size==2*nk floats).

#define NCOL 1024
#define NROWIMG 1024
#define H2 1048576.0f
#define OMG 80.0f

// ---------------- hot path: interleaved in / interleaved out, 4 complex/thread
__global__ __launch_bounds__(256) void helm_v4(
    const float4* __restrict__ x4,   // 2 complex per float4; nk/2 entries
    const float4* __restrict__ k4,   // 4 floats per entry; nk/4 entries
    const float4* __restrict__ g4,
    float4* __restrict__ o4)         // same layout as x4
{
    const int t  = blockIdx.x * blockDim.x + threadIdx.x;  // 0 .. nk/4-1
    const int cg = t & 255;                 // column group; first col j4 = cg*4
    const int row = t >> 8;                 // global row = b*1024 + i
    const int i  = row & (NROWIMG - 1);

    const long cbase = 2L * t;              // float4 index of this thread's 4 complex
    const float4 ca = x4[cbase];            // c0r c0i c1r c1i
    const float4 cb = x4[cbase + 1];        // c2r c2i c3r c3i

    float4 ua, ub, da, db;
    if (i > 0)            { ua = x4[cbase - 512]; ub = x4[cbase - 511]; }
    else                  { ua = make_float4(0,0,0,0); ub = ua; }
    if (i < NROWIMG - 1)  { da = x4[cbase + 512]; db = x4[cbase + 513]; }
    else                  { da = make_float4(0,0,0,0); db = da; }

    float2 lf = make_float2(0.f, 0.f);
    float2 rt = make_float2(0.f, 0.f);
    const float2* x2 = (const float2*)x4;
    const long ebase = 4L * t;              // complex-element index of c0
    if (cg > 0)   lf = x2[ebase - 1];
    if (cg < 255) rt = x2[ebase + 4];

    const float4 kk = k4[t];
    const float4 gg = g4[t];

    // helm = kappa^2*OMEGA*(OMEGA - i*gamma) = hr + i*hi
    const float ks0 = kk.x * kk.x, ks1 = kk.y * kk.y, ks2 = kk.z * kk.z, ks3 = kk.w * kk.w;
    const float hr0 = OMG * OMG * ks0, hr1 = OMG * OMG * ks1;
    const float hr2 = OMG * OMG * ks2, hr3 = OMG * OMG * ks3;
    const float hi0 = -OMG * ks0 * gg.x, hi1 = -OMG * ks1 * gg.y;
    const float hi2 = -OMG * ks2 * gg.z, hi3 = -OMG * ks3 * gg.w;

    // Laplacian: left of c0 = lf, left of c1 = c0, ... ; right of c3 = rt.
    float4 oa, ob;
    oa.x = (4.f*ca.x - ua.x - da.x - lf.x - ca.z) * H2 - (hr0*ca.x - hi0*ca.y);
    oa.y = (4.f*ca.y - ua.y - da.y - lf.y - ca.w) * H2 - (hr0*ca.y + hi0*ca.x);
    oa.z = (4.f*ca.z - ua.z - da.z - ca.x - cb.x) * H2 - (hr1*ca.z - hi1*ca.w);
    oa.w = (4.f*ca.w - ua.w - da.w - ca.y - cb.y) * H2 - (hr1*ca.w + hi1*ca.z);
    ob.x = (4.f*cb.x - ub.x - db.x - ca.z - cb.z) * H2 - (hr2*cb.x - hi2*cb.y);
    ob.y = (4.f*cb.y - ub.y - db.y - ca.w - cb.w) * H2 - (hr2*cb.y + hi2*cb.x);
    ob.z = (4.f*cb.z - ub.z - db.z - cb.x - rt.x) * H2 - (hr3*cb.z - hi3*cb.w);
    ob.w = (4.f*cb.w - ub.w - db.w - cb.y - rt.y) * H2 - (hr3*cb.w + hi3*cb.x);

    o4[cbase]     = oa;
    o4[cbase + 1] = ob;
}

// ---------------- safe fallback (proven correct round 2), any layout ----------
__global__ __launch_bounds__(256) void helm_adapt(
    const float* __restrict__ xa,
    const float* __restrict__ xb,
    const float* __restrict__ kap,
    const float* __restrict__ gma,
    float* __restrict__ out,
    int nk, int world, int omode)
{
    const int e = blockIdx.x * blockDim.x + threadIdx.x;
    if (e >= nk) return;
    const int col = e & (NCOL - 1);
    const int row = e >> 10;
    const int i   = row & (NROWIMG - 1);

    float cr, ci;
    float ur = 0.f, ui = 0.f, dr = 0.f, di = 0.f;
    float lr = 0.f, li = 0.f, rr = 0.f, ri = 0.f;

    if (world == 0) {
        const float2* x2 = (const float2*)xa;
        float2 c = x2[e]; cr = c.x; ci = c.y;
        if (i > 0)          { float2 tv = x2[e - NCOL]; ur = tv.x; ui = tv.y; }
        if (i < NROWIMG - 1){ float2 tv = x2[e + NCOL]; dr = tv.x; di = tv.y; }
        if (col > 0)        { float2 tv = x2[e - 1];    lr = tv.x; li = tv.y; }
        if (col < NCOL - 1) { float2 tv = x2[e + 1];    rr = tv.x; ri = tv.y; }
    } else if (world == 1) {
        cr = xa[e]; ci = xb[e];
        if (i > 0)          { ur = xa[e - NCOL]; ui = xb[e - NCOL]; }
        if (i < NROWIMG - 1){ dr = xa[e + NCOL]; di = xb[e + NCOL]; }
        if (col > 0)        { lr = xa[e - 1];    li = xb[e - 1]; }
        if (col < NCOL - 1) { rr = xa[e + 1];    ri = xb[e + 1]; }
    } else {
        cr = xa[e]; ci = 0.f;
        if (i > 0)          ur = xa[e - NCOL];
        if (i < NROWIMG - 1) dr = xa[e + NCOL];
        if (col > 0)        lr = xa[e - 1];
        if (col < NCOL - 1) rr = xa[e + 1];
    }

    const float kk = kap[e];
    const float gg = gma[e];

    const float lapr = (4.f * cr - ur - dr - lr - rr) * H2;
    const float lapi = (4.f * ci - ui - di - li - ri) * H2;
    const float ks = kk * kk;
    const float hr = OMG * OMG * ks;
    const float hi = -OMG * ks * gg;
    const float or_ = lapr - (hr * cr - hi * ci);
    const float oi_ = lapi - (hr * ci + hi * cr);

    if (omode == 0) {
        ((float2*)out)[e] = make_float2(or_, oi_);
    } else if (omode == 1) {
        out[e] = or_;
        out[nk + e] = oi_;
    } else {
        out[e] = or_;
    }
}

extern "C" void kernel_launch(void* const* d_in, const int* in_sizes, int n_in,
                              void* d_out, int out_size, void* d_ws, size_t ws_size,
                              hipStream_t stream) {
    const int nk = in_sizes[n_in - 2];            // complex-element count (float kappa)
    const float* kap = (const float*)d_in[n_in - 2];
    const float* gma = (const float*)d_in[n_in - 1];
    const float* xa  = (const float*)d_in[0];
    const float* xb  = nullptr;

    int world;
    if (n_in >= 4)                    { world = 1; xb = (const float*)d_in[1]; }
    else if (in_sizes[0] >= 2 * nk)   { world = 0; }
    else                              { world = 2; }

    int omode;
    if (out_size >= 2 * nk) omode = (world == 1) ? 1 : 0;
    else                    omode = 2;

    const int block = 256;

    // Hot path: confirmed interleaved layout + exact geometry.
    if (world == 0 && omode == 0 && nk == 8 * 1024 * 1024) {
        const int grid = nk / 4 / block;          // 8192
        helm_v4<<<grid, block, 0, stream>>>((const float4*)xa, (const float4*)kap,
                                            (const float4*)gma, (float4*)d_out);
    } else {
        const int grid = (nk + block - 1) / block;
        helm_adapt<<<grid, block, 0, stream>>>(xa, xb, kap, gma, (float*)d_out,
                                               nk, world, omode);
    }
}